// Round 3
// baseline (282.576 us; speedup 1.0000x reference)
//
#include <hip/hip_runtime.h>

// out[..., m] = b[..., m] + ALPHA * b[..., m+1]  (m < 39);  out[..., 39] = b[..., 39]
// b: (16, 65536, 40) float32, flat n = 41,943,040. Row = 40 floats = 10 float4s,
// so within any float4 (index i) only .w can be the row-last coeff, exactly
// when i % 10 == 9.

static constexpr float kAlpha = 0.42f;

typedef float f32x4 __attribute__((ext_vector_type(4)));  // native vector: OK for nontemporal builtins

__global__ void __launch_bounds__(256)
b2mc_kernel(const float* __restrict__ b, float* __restrict__ out, int n4) {
    const f32x4* __restrict__ b4 = reinterpret_cast<const f32x4*>(b);
    f32x4* __restrict__ o4 = reinterpret_cast<f32x4*>(out);
    const int S = gridDim.x * blockDim.x;
    const bool lane63 = ((threadIdx.x & 63) == 63);

    int i0 = blockIdx.x * blockDim.x + threadIdx.x;
    int i1 = i0 + S;
    // Phase (i % 10) tracked incrementally: one magic-mod here, adds thereafter.
    int p0 = i0 % 10;
    int p1 = i1 % 10;
    const int dp = (2 * S) % 10;

    while (i1 < n4) {
        // Issue both 16B loads before any dependent work (MLP).
        f32x4 v0 = b4[i0];
        f32x4 v1 = b4[i1];

        // Shifted neighbor for elem 3 is the next float4's elem 0. Consecutive
        // lanes hold consecutive float4 indices; lane 63 falls back to a real
        // (L1/L2-hit) load.
        float nxt0 = __shfl_down(v0.x, 1);
        float nxt1 = __shfl_down(v1.x, 1);
        const bool re0 = (p0 == 9);   // element 4*i0+3 is m==39 of its row
        const bool re1 = (p1 == 9);
        if (lane63) {
            if (!re0) nxt0 = b[4 * i0 + 4];   // !rowend => in-bounds (n % 40 == 0)
            if (!re1) nxt1 = b[4 * i1 + 4];
        }
        f32x4 r0, r1;
        r0.x = fmaf(kAlpha, v0.y, v0.x);
        r0.y = fmaf(kAlpha, v0.z, v0.y);
        r0.z = fmaf(kAlpha, v0.w, v0.z);
        r0.w = re0 ? v0.w : fmaf(kAlpha, nxt0, v0.w);
        r1.x = fmaf(kAlpha, v1.y, v1.x);
        r1.y = fmaf(kAlpha, v1.z, v1.y);
        r1.z = fmaf(kAlpha, v1.w, v1.z);
        r1.w = re1 ? v1.w : fmaf(kAlpha, nxt1, v1.w);

        // Nontemporal: output is write-once — don't evict the L3-resident input.
        __builtin_nontemporal_store(r0, &o4[i0]);
        __builtin_nontemporal_store(r1, &o4[i1]);

        i0 += 2 * S;
        i1 += 2 * S;
        p0 += dp; if (p0 >= 10) p0 -= 10;
        p1 += dp; if (p1 >= 10) p1 -= 10;
    }
    // Tail (dead for the bench shape; kept for generality).
    if (i0 < n4) {
        f32x4 v0 = b4[i0];
        float nxt0 = __shfl_down(v0.x, 1);
        const bool re0 = (p0 == 9);
        if (lane63 && !re0) nxt0 = b[4 * i0 + 4];
        f32x4 r0;
        r0.x = fmaf(kAlpha, v0.y, v0.x);
        r0.y = fmaf(kAlpha, v0.z, v0.y);
        r0.z = fmaf(kAlpha, v0.w, v0.z);
        r0.w = re0 ? v0.w : fmaf(kAlpha, nxt0, v0.w);
        __builtin_nontemporal_store(r0, &o4[i0]);
    }
}

extern "C" void kernel_launch(void* const* d_in, const int* in_sizes, int n_in,
                              void* d_out, int out_size, void* d_ws, size_t ws_size,
                              hipStream_t stream) {
    const float* b = (const float*)d_in[0];
    float* out = (float*)d_out;
    const int n = in_sizes[0];       // 41,943,040
    const int n4 = n / 4;            // 10,485,760 float4s
    const int block = 256;
    int grid = 2048;                 // 8 blocks/CU on 256 CUs; grid-stride the rest
    const int need = (n4 + block - 1) / block;
    if (need < grid) grid = need;
    b2mc_kernel<<<grid, block, 0, stream>>>(b, out, n4);
}